// Round 2
// 389.927 us; speedup vs baseline: 1.0868x; 1.0868x over previous
//
#include <hip/hip_runtime.h>
#include <hip/hip_bf16.h>
#include <stdint.h>

// FusedLinearCrossEntropyLoss on MI355X (gfx950)
// loss = mean_i( logsumexp_j(x_i . w_j + b_j) - (x_i . w_t(i) + b_t(i)) )
//
// R7 (resubmit; round 1 was a broker timeout, no data):
//     LDS-STAGED GEMM with counted-vmcnt double buffering.
//     R6's no-LDS loop was L2-BW-bound (~19 TB/s demand, 48 KB/block/kg with
//     2x duplicate loads across waves). Now each k-group is staged ONCE into
//     LDS via global_load_lds (24 KB/block/kg: A 16KB + B 8KB), waves read
//     frags via conflict-free ds_read_b128 (chunk layout is fragment-native,
//     so LDS copy is linear). Pipeline: 2 LDS buffers, prefetch depth 2,
//     s_waitcnt vmcnt(6) counted (never drained to 0 in steady state), raw
//     s_barrier (no __syncthreads vmcnt(0) drain), s_setprio(1) around MFMAs.
//     Plus bijective XCD swizzle (4000 blocks % 8 == 0) so the 16 row-blocks
//     sharing one W tile land in one XCD's L2.
//
// Chunk layout: chunk c = R*16 + g (R = 32-row block, g = 64-wide k group).
// Within chunk: half h in {0,1}, lane l in 0..63, byte j in 0..15:
//   data[c*2048 + h*1024 + l*16 + j] = M[R*32 + (l&31)][g*64 + (l>>5)*32 + h*16 + j]

typedef float f16v __attribute__((ext_vector_type(16)));
typedef int v8i __attribute__((ext_vector_type(8)));

__device__ __forceinline__ unsigned pk_fp8(float4 v) {
  int w = 0;
  w = __builtin_amdgcn_cvt_pk_fp8_f32(v.x, v.y, w, false);  // bytes 0,1
  w = __builtin_amdgcn_cvt_pk_fp8_f32(v.z, v.w, w, true);   // bytes 2,3
  return (unsigned)w;
}

// fp32 [N x 1024] -> fp8 fragment-swizzled chunks. One thread = 16 out bytes.
__global__ __launch_bounds__(256) void cast_swz_k(const float* __restrict__ in,
                                                  uint4* __restrict__ out,
                                                  long n16) {
  long t = (long)blockIdx.x * blockDim.x + threadIdx.x;
  long stride = (long)gridDim.x * blockDim.x;
  for (; t < n16; t += stride) {
    long o = t * 16;
    int c = (int)(o >> 11);
    int rem = (int)(o & 2047);
    int h = rem >> 10;
    int lam = (rem >> 4) & 63;
    int row = (c >> 4) * 32 + (lam & 31);
    int k = (c & 15) * 64 + (lam >> 5) * 32 + h * 16;
    const float4* src = (const float4*)(in + (long)row * 1024 + k);
    uint4 oo;
    oo.x = pk_fp8(src[0]); oo.y = pk_fp8(src[1]);
    oo.z = pk_fp8(src[2]); oo.w = pk_fp8(src[3]);
    out[t] = oo;
  }
}

// One block per row: x_y[row] = x[row] . W[safe_t] + bias[safe_t]  (fp32, exact)
__global__ __launch_bounds__(256) void xy_k(const float* __restrict__ x,
                                            const float* __restrict__ w,
                                            const float* __restrict__ bias,
                                            const int* __restrict__ tgt,
                                            float* __restrict__ xy, int H, int V) {
  int row = blockIdx.x;
  int t = tgt[row];
  int st = min(max(t, 0), V - 1);
  const float4* xr = (const float4*)(x + (long)row * H);
  const float4* wr = (const float4*)(w + (long)st * H);
  float s = 0.f;
  int n4 = H >> 2;
  for (int i = threadIdx.x; i < n4; i += 256) {
    float4 a = xr[i], b = wr[i];
    s += a.x * b.x + a.y * b.y + a.z * b.z + a.w * b.w;
  }
  for (int off = 32; off; off >>= 1) s += __shfl_down(s, off, 64);
  __shared__ float sm[4];
  if ((threadIdx.x & 63) == 0) sm[threadIdx.x >> 6] = s;
  __syncthreads();
  if (threadIdx.x == 0) xy[row] = sm[0] + sm[1] + sm[2] + sm[3] + bias[st];
}

// 256x128 block tile, 4 waves in 2x2; each wave 128x64 via 4x2 of 32x32x64.
// LDS-staged, double-buffered, counted vmcnt. Per k-group per buffer:
//   A chunks 0..7 at [i*2048], B chunks 0..3 at [16384 + j*2048]  (24 KB).
// Epilogue: partials[bn][row] = sum_cols exp(logit + bias).
#define LDS_BUF 24576

__global__ __launch_bounds__(256, 2)
void gemm_sumexp(const char* __restrict__ Xf, const char* __restrict__ Wf,
                 const float* __restrict__ bias, float* __restrict__ partials,
                 int H, int BT) {
  __shared__ char lds[2 * LDS_BUF];
  __shared__ float rowsum[2][256];

  const int tid = threadIdx.x;
  const int w = tid >> 6, lane = tid & 63;
  const int wr = w >> 1, wc = w & 1;
  const int l32 = lane & 31, kh = lane >> 5;

  // Bijective XCD-aware swizzle: contiguous swz chunks per XCD so the 16
  // row-blocks of one column tile (same W panel) share one XCD's L2.
  const int nbx = gridDim.x;
  const int nwg = nbx * gridDim.y;
  const int id = blockIdx.y * nbx + blockIdx.x;
  const int swz = ((nwg & 7) == 0) ? ((id & 7) * (nwg >> 3) + (id >> 3)) : id;
  const int bx = swz % nbx;
  const int by = swz / nbx;
  const int m0 = bx * 256, n0 = by * 128;

  // Staging: 24 segments of 1KB per k-group (A 16 segs, B 8 segs).
  // Wave w stages segments 6w..6w+5. gl_lds dest = uniform base + lane*16.
  const char* segsrc[6];
  int segdst[6];
#pragma unroll
  for (int r = 0; r < 6; ++r) {
    const int s = w * 6 + r;
    if (s < 16) {
      long base = (long)(bx * 8 + (s >> 1)) * 32768 + (long)(s & 1) * 1024;
      segsrc[r] = Xf + base + lane * 16;
    } else {
      long base = (long)(by * 4 + ((s - 16) >> 1)) * 32768 + (long)((s - 16) & 1) * 1024;
      segsrc[r] = Wf + base + lane * 16;
    }
    segdst[r] = s * 1024;
  }

  auto STAGE = [&](int g) {
    const int bo = (g & 1) * LDS_BUF;
#pragma unroll
    for (int r = 0; r < 6; ++r)
      __builtin_amdgcn_global_load_lds(
          (const __attribute__((address_space(1))) void*)(segsrc[r] + (long)g * 2048),
          (__attribute__((address_space(3))) void*)(lds + bo + segdst[r]),
          16, 0, 0);
  };

  f16v acc[4][2];
#pragma unroll
  for (int mi = 0; mi < 4; mi++)
#pragma unroll
    for (int ni = 0; ni < 2; ni++)
#pragma unroll
      for (int r = 0; r < 16; r++) acc[mi][ni][r] = 0.f;

  const int nG = H >> 6;  // 16 k-groups of 64 (requires nG >= 2)

  // Prologue: fill both buffers, wait only for buffer 0 (counted).
  STAGE(0);
  STAGE(1);
  asm volatile("s_waitcnt vmcnt(6)" ::: "memory");
  __builtin_amdgcn_s_barrier();

#pragma unroll 2
  for (int g = 0; g < nG; ++g) {
    const int bo = (g & 1) * LDS_BUF;
    v8i a[4], b[2];
#pragma unroll
    for (int mi = 0; mi < 4; mi++) {
      const char* p = lds + bo + (wr * 4 + mi) * 2048 + lane * 16;
      int4 lo = *(const int4*)(p);
      int4 hi = *(const int4*)(p + 1024);
      v8i t;
      t[0] = lo.x; t[1] = lo.y; t[2] = lo.z; t[3] = lo.w;
      t[4] = hi.x; t[5] = hi.y; t[6] = hi.z; t[7] = hi.w;
      a[mi] = t;
    }
#pragma unroll
    for (int ni = 0; ni < 2; ni++) {
      const char* p = lds + bo + 16384 + (wc * 2 + ni) * 2048 + lane * 16;
      int4 lo = *(const int4*)(p);
      int4 hi = *(const int4*)(p + 1024);
      v8i t;
      t[0] = lo.x; t[1] = lo.y; t[2] = lo.z; t[3] = lo.w;
      t[4] = hi.x; t[5] = hi.y; t[6] = hi.z; t[7] = hi.w;
      b[ni] = t;
    }
    __builtin_amdgcn_s_setprio(1);
#pragma unroll
    for (int mi = 0; mi < 4; mi++)
#pragma unroll
      for (int ni = 0; ni < 2; ni++)
        acc[mi][ni] = __builtin_amdgcn_mfma_scale_f32_32x32x64_f8f6f4(
            a[mi], b[ni], acc[mi][ni], 0 /*A=fp8*/, 0 /*B=fp8*/,
            0, 127 /*scale_a = 1.0*/, 0, 127 /*scale_b = 1.0*/);
    __builtin_amdgcn_s_setprio(0);

    // All waves done reading buf[g&1] -> safe to refill it.
    __builtin_amdgcn_s_barrier();
    if (g + 2 < nG) {
      STAGE(g + 2);
      // 12 outstanding (6 for g+1, 6 for g+2); wait until only g+2's remain.
      asm volatile("s_waitcnt vmcnt(6)" ::: "memory");
    } else {
      asm volatile("s_waitcnt vmcnt(0)" ::: "memory");
    }
    __builtin_amdgcn_s_barrier();
  }

  // ---- epilogue: per-row sum of exp(logit + bias) ----
  // C/D 32x32 layout: col = lane&31, row = (reg&3) + 8*(reg>>2) + 4*(lane>>5)
  float bv[2];
  bv[0] = bias[n0 + wc * 64 + l32];
  bv[1] = bias[n0 + wc * 64 + 32 + l32];

#pragma unroll
  for (int mi = 0; mi < 4; mi++) {
    float p[16];
#pragma unroll
    for (int r = 0; r < 16; r++) p[r] = 0.f;
#pragma unroll
    for (int ni = 0; ni < 2; ni++)
#pragma unroll
      for (int r = 0; r < 16; r++) p[r] += __expf(acc[mi][ni][r] + bv[ni]);
    // reduce across the 32 columns (lanes within each 32-group)
#pragma unroll
    for (int off = 1; off < 32; off <<= 1)
#pragma unroll
      for (int r = 0; r < 16; r++) p[r] += __shfl_xor(p[r], off, 32);
    if (l32 == 0) {
#pragma unroll
      for (int r = 0; r < 16; r++)
        rowsum[wc][wr * 128 + mi * 32 + (r & 3) + 8 * (r >> 2) + 4 * kh] = p[r];
    }
  }
  __syncthreads();
  partials[(long)by * BT + m0 + tid] = rowsum[0][tid] + rowsum[1][tid];
}

// per-row: lse - x_y ; 4 threads per row for b-parallelism, 64 rows/block
__global__ __launch_bounds__(256)
void row_reduce(const float* __restrict__ partials, const float* __restrict__ xy,
                const int* __restrict__ tgt, float* __restrict__ bsum,
                float* __restrict__ bcnt, int BT, int nCB) {
  const int row = blockIdx.x * 64 + (threadIdx.x >> 2);
  const int q = threadIdx.x & 3;
  float S = 0.f;
  for (int b = q; b < nCB; b += 4) S += partials[(long)b * BT + row];
  S += __shfl_xor(S, 1, 64);
  S += __shfl_xor(S, 2, 64);
  float pr = 0.f, c = 0.f;
  if (q == 0) {
    int t = tgt[row];
    if (t != -100) { pr = logf(S) - xy[row]; c = 1.f; }
  }
  for (int off = 32; off; off >>= 1) {
    pr += __shfl_down(pr, off, 64);
    c += __shfl_down(c, off, 64);
  }
  __shared__ float sp[4], sc[4];
  if ((threadIdx.x & 63) == 0) {
    sp[threadIdx.x >> 6] = pr;
    sc[threadIdx.x >> 6] = c;
  }
  __syncthreads();
  if (threadIdx.x == 0) {
    bsum[blockIdx.x] = sp[0] + sp[1] + sp[2] + sp[3];
    bcnt[blockIdx.x] = sc[0] + sc[1] + sc[2] + sc[3];
  }
}

__global__ void finalize(const float* __restrict__ bsum, const float* __restrict__ bcnt,
                         float* __restrict__ out, int nb) {
  float s = 0.f, c = 0.f;
  for (int i = threadIdx.x; i < nb; i += 64) { s += bsum[i]; c += bcnt[i]; }
  for (int off = 32; off; off >>= 1) {
    s += __shfl_down(s, off, 64);
    c += __shfl_down(c, off, 64);
  }
  if (threadIdx.x == 0) out[0] = s / c;
}

extern "C" void kernel_launch(void* const* d_in, const int* in_sizes, int n_in,
                              void* d_out, int out_size, void* d_ws, size_t ws_size,
                              hipStream_t stream) {
  const float* x = (const float*)d_in[0];
  const int* tgt = (const int*)d_in[1];
  const float* w = (const float*)d_in[2];
  const float* bias = (const float*)d_in[3];
  float* out = (float*)d_out;

  const int BT = in_sizes[1];            // 4096
  const int V = in_sizes[3];             // 32000
  const int H = in_sizes[0] / BT;        // 1024
  const int nCB = V / 128;               // 250 column blocks

  char* ws = (char*)d_ws;
  const long wb_bytes = (long)V * H;     // fp8: 1 B/elem
  const long xb_bytes = (long)BT * H;
  char* Wf = ws;
  char* Xf = ws + wb_bytes;
  float* partials = (float*)(ws + wb_bytes + xb_bytes);
  float* xy = partials + (long)nCB * BT;
  float* bsum = xy + BT;
  float* bcnt = bsum + (BT / 64);

  cast_swz_k<<<8192, 256, 0, stream>>>(w, (uint4*)Wf, (long)V * H / 16);
  cast_swz_k<<<1024, 256, 0, stream>>>(x, (uint4*)Xf, (long)BT * H / 16);
  xy_k<<<BT, 256, 0, stream>>>(x, w, bias, tgt, xy, H, V);
  dim3 grid(BT / 256, nCB);
  gemm_sumexp<<<grid, 256, 0, stream>>>(Xf, Wf, bias, partials, H, BT);
  row_reduce<<<BT / 64, 256, 0, stream>>>(partials, xy, tgt, bsum, bcnt, BT, nCB);
  finalize<<<1, 64, 0, stream>>>(bsum, bcnt, out, BT / 64);
}